// Round 1
// baseline (848.546 us; speedup 1.0000x reference)
//
#include <hip/hip_runtime.h>

#define WG 256
#define NB 4      // b-values per block
#define GMAX 64   // graphs

// nh[n][t] = sum_f x[n][f] * v[f][t]   (F=3, T=32 hardcoded)
__global__ __launch_bounds__(WG) void k_nh(const float* __restrict__ x,
                                           const float* __restrict__ v,
                                           float* __restrict__ nh, int N) {
    int idx = blockIdx.x * WG + threadIdx.x;
    if (idx >= N * 32) return;
    int n = idx >> 5;
    int t = idx & 31;
    const float* xr = x + n * 3;
    nh[idx] = xr[0] * v[t] + xr[1] * v[32 + t] + xr[2] * v[64 + t];
}

// eh[e][t] = max(nh[src][t], nh[dst][t]);  eg[e] = batch[src]
__global__ __launch_bounds__(WG) void k_eh(const int* __restrict__ edge,
                                           const int* __restrict__ batch,
                                           const float* __restrict__ nh,
                                           float* __restrict__ eh,
                                           int* __restrict__ eg, int E) {
    int idx = blockIdx.x * WG + threadIdx.x;
    if (idx >= E * 32) return;
    int e = idx >> 5;
    int t = idx & 31;
    int s = edge[e];
    int d = edge[E + e];
    eh[idx] = fmaxf(nh[(s << 5) + t], nh[(d << 5) + t]);
    if (t == 0) eg[e] = batch[s];
}

// Accumulate sigmoid contributions for NB consecutive b-values into an LDS
// table [NB][GMAX][32], then flush to global with HW fp32 atomics.
// Items 0..N-1 are nodes (sign +1), N..N+E-1 are edges (sign -1).
__global__ __launch_bounds__(WG) void k_acc(const float* __restrict__ nh,
                                            const float* __restrict__ eh,
                                            const int* __restrict__ batch,
                                            const int* __restrict__ eg,
                                            const float* __restrict__ lin,
                                            float* __restrict__ out,
                                            int N, int E, int ipc) {
    __shared__ float lds[NB * GMAX * 32];
    int tid = threadIdx.x;
    for (int i = tid; i < NB * GMAX * 32; i += WG) lds[i] = 0.f;
    __syncthreads();

    int b0 = blockIdx.y * NB;
    float l0 = 200.f * lin[b0];
    float l1 = 200.f * lin[b0 + 1];
    // exp(200h - l_{b+1}) = exp(200h - l_b) * fstep  (uniform threshold grid)
    float fstep = __expf(l0 - l1);

    int t = tid & 31;
    int sub = tid >> 5;   // 0..7: item sub-lane within block
    int M = N + E;
    int start = blockIdx.x * ipc;
    int end = start + ipc;
    if (end > M) end = M;

    for (int i = start + sub; i < end; i += (WG >> 5)) {
        float h, sgn;
        int g;
        if (i < N) {
            h = nh[(i << 5) + t];
            g = batch[i];
            sgn = 1.f;
        } else {
            int e = i - N;
            h = eh[(e << 5) + t];
            g = eg[e];
            sgn = -1.f;
        }
        float e0 = __expf(200.f * h - l0);   // sigmoid = 1/(1+e0)
        float* cell = &lds[(g << 5) + t];
        #pragma unroll
        for (int b = 0; b < NB; ++b) {
            float s = __builtin_amdgcn_rcpf(1.f + e0);
            unsafeAtomicAdd(cell + b * (GMAX * 32), sgn * s);
            e0 *= fstep;
        }
    }
    __syncthreads();

    // flush: out[(g*32 + b0 + bs)*32 + tt] += lds[bs][g][tt]
    for (int c = tid; c < NB * GMAX * 32; c += WG) {
        float val = lds[c];
        if (val != 0.f) {
            int tt = c & 31;
            int g = (c >> 5) & (GMAX - 1);
            int bs = c >> 11;
            unsafeAtomicAdd(&out[(((g << 5) + b0 + bs) << 5) + tt], val);
        }
    }
}

extern "C" void kernel_launch(void* const* d_in, const int* in_sizes, int n_in,
                              void* d_out, int out_size, void* d_ws, size_t ws_size,
                              hipStream_t stream) {
    const float* x     = (const float*)d_in[0];
    const float* v     = (const float*)d_in[1];
    const float* lin   = (const float*)d_in[2];
    const int*   edge  = (const int*)d_in[3];
    const int*   batch = (const int*)d_in[4];
    // sizes: x = N*3, v = 96, lin = 32, edge = 2*E, batch = N
    int N = in_sizes[4];
    int E = in_sizes[3] / 2;

    float* out = (float*)d_out;
    float* nh  = (float*)d_ws;                 // N*32 floats
    float* eh  = nh + (size_t)N * 32;          // E*32 floats
    int*   eg  = (int*)(eh + (size_t)E * 32);  // E ints

    hipMemsetAsync(d_out, 0, (size_t)out_size * sizeof(float), stream);

    k_nh<<<(N * 32 + WG - 1) / WG, WG, 0, stream>>>(x, v, nh, N);
    k_eh<<<(E * 32 + WG - 1) / WG, WG, 0, stream>>>(edge, batch, nh, eh, eg, E);

    int M = N + E;
    int chunks = 96;                 // grid = 96 x 8 = 768 blocks (~3/CU)
    int ipc = (M + chunks - 1) / chunks;
    dim3 grid(chunks, 32 / NB);
    k_acc<<<grid, WG, 0, stream>>>(nh, eh, batch, eg, lin, out, N, E, ipc);
}

// Round 2
// 133.834 us; speedup vs baseline: 6.3403x; 6.3403x over previous
//
#include <hip/hip_runtime.h>

#define WG 256
#define G64 64     // num_graphs (fixed by problem)
#define SPLITS 16  // blocks per graph in k_acc

// ---------------------------------------------------------------------------
// k_hist: per-edge graph id eg[e] = batch[src]; histogram into cnt[64]
// ---------------------------------------------------------------------------
__global__ __launch_bounds__(WG) void k_hist(const int* __restrict__ edge,
                                             const int* __restrict__ batch,
                                             int* __restrict__ eg,
                                             int* __restrict__ cnt, int E) {
    __shared__ int lc[G64];
    int tid = threadIdx.x;
    if (tid < G64) lc[tid] = 0;
    __syncthreads();
    int e = blockIdx.x * WG + tid;
    if (e < E) {
        int g = batch[edge[e]];
        eg[e] = g;
        atomicAdd(&lc[g], 1);
    }
    __syncthreads();
    if (tid < G64 && lc[tid]) atomicAdd(&cnt[tid], lc[tid]);
}

// ---------------------------------------------------------------------------
// k_scan: 1 block. offs = exclusive scan of cnt (edges), cursor = copy,
// node_off[g] = lower_bound(batch, g) (batch is sorted).
// ---------------------------------------------------------------------------
__global__ __launch_bounds__(128) void k_scan(const int* __restrict__ batch,
                                              const int* __restrict__ cnt,
                                              int* __restrict__ offs,
                                              int* __restrict__ cursor,
                                              int* __restrict__ node_off, int N) {
    int tid = threadIdx.x;
    if (tid <= G64) {
        int lo = 0, hi = N;
        while (lo < hi) {
            int mid = (lo + hi) >> 1;
            if (batch[mid] < tid) lo = mid + 1; else hi = mid;
        }
        node_off[tid] = lo;
    }
    if (tid == 0) {
        int s = 0;
        for (int g = 0; g < G64; ++g) { offs[g] = s; cursor[g] = s; s += cnt[g]; }
        offs[G64] = s;
    }
}

// ---------------------------------------------------------------------------
// k_scatter: counting-sort placement. Block-aggregated cursor bump (64 global
// atomics per block instead of per-edge same-address contention).
// ---------------------------------------------------------------------------
__global__ __launch_bounds__(WG) void k_scatter(const int* __restrict__ eg,
                                                int* __restrict__ cursor,
                                                int* __restrict__ perm, int E) {
    __shared__ int lc[G64], lb[G64];
    int tid = threadIdx.x;
    if (tid < G64) lc[tid] = 0;
    __syncthreads();
    int e = blockIdx.x * WG + tid;
    int g = 0, r = 0;
    if (e < E) { g = eg[e]; r = atomicAdd(&lc[g], 1); }
    __syncthreads();
    if (tid < G64 && lc[tid]) lb[tid] = atomicAdd(&cursor[tid], lc[tid]);
    __syncthreads();
    if (e < E) perm[lb[g] + r] = e;
}

// ---------------------------------------------------------------------------
// k_eh2: ehs[pos][t] = max over the edge's two endpoints of (x[node] . v[:,t]),
// in graph-sorted edge order. Heights recomputed from x (12 B broadcast per
// endpoint instead of a 128 B nh row).
// ---------------------------------------------------------------------------
__global__ __launch_bounds__(WG) void k_eh2(const int* __restrict__ perm,
                                            const int* __restrict__ edge,
                                            const float* __restrict__ x,
                                            const float* __restrict__ v,
                                            float* __restrict__ ehs, int E) {
    int idx = blockIdx.x * WG + threadIdx.x;
    if (idx >= E * 32) return;
    int pos = idx >> 5, t = idx & 31;
    int e = perm[pos];
    int s = edge[e], d = edge[E + e];
    float v0 = v[t], v1 = v[32 + t], v2 = v[64 + t];
    const float* xs = x + s * 3;
    const float* xd = x + d * 3;
    float hs = xs[0] * v0 + xs[1] * v1 + xs[2] * v2;
    float hd = xd[0] * v0 + xd[1] * v1 + xd[2] * v2;
    ehs[idx] = fmaxf(hs, hd);
}

// ---------------------------------------------------------------------------
// k_acc: block (g, split) owns one graph -> pure register accumulation.
// Item stream per graph: nodes [node_off[g], node_off[g+1]) then sorted edges
// [offs[g], offs[g+1]). acc[32] registers (one per threshold b), one exp per
// 4 thresholds via e_{b+1} = e_b * fstep (anchor spacing 4 keeps fp32
// overflow consistent with saturated sigmoid). Flush once: shfl halves ->
// LDS stage[4 waves][32b][32t] -> 1024 global atomics per block.
// ---------------------------------------------------------------------------
__global__ __launch_bounds__(WG) void k_acc(const float* __restrict__ x,
                                            const float* __restrict__ v,
                                            const float* __restrict__ ehs,
                                            const float* __restrict__ lin,
                                            const int* __restrict__ offs,
                                            const int* __restrict__ node_off,
                                            float* __restrict__ out) {
    int g = blockIdx.x;
    int n0 = node_off[g], n1 = node_off[g + 1];
    int e0 = offs[g], e1 = offs[g + 1];
    int nn = n1 - n0;
    int L = nn + (e1 - e0);
    int ipc = (L + SPLITS - 1) / SPLITS;
    int lo = blockIdx.y * ipc;
    int hi = lo + ipc; if (hi > L) hi = L;

    int tid = threadIdx.x, t = tid & 31, sub = tid >> 5;
    float v0 = v[t], v1 = v[32 + t], v2 = v[64 + t];

    float l[8];
#pragma unroll
    for (int a = 0; a < 8; ++a) l[a] = 200.f * lin[4 * a];
    float fstep = __expf(200.f * (lin[0] - lin[1]));   // exp(-200*dlin)

    float acc[32];
#pragma unroll
    for (int b = 0; b < 32; ++b) acc[b] = 0.f;

    for (int idx = lo + sub; idx < hi; idx += 8) {
        float h, sgn;
        if (idx < nn) {
            const float* xr = x + (n0 + idx) * 3;
            h = xr[0] * v0 + xr[1] * v1 + xr[2] * v2;
            sgn = 1.f;
        } else {
            h = ehs[((e0 + idx - nn) << 5) + t];
            sgn = -1.f;
        }
        float h200 = 200.f * h;
#pragma unroll
        for (int a = 0; a < 8; ++a) {
            float e = __expf(h200 - l[a]);
#pragma unroll
            for (int j = 0; j < 4; ++j) {
                acc[4 * a + j] += sgn * __builtin_amdgcn_rcpf(1.f + e);
                e *= fstep;
            }
        }
    }

    // --- block reduce + flush ---
    __shared__ float stage[4 * 1024];
#pragma unroll
    for (int b = 0; b < 32; ++b) acc[b] += __shfl_xor(acc[b], 32, 64);
    int w = tid >> 6;
    if ((tid & 32) == 0) {
#pragma unroll
        for (int b = 0; b < 32; ++b) stage[(w << 10) + (b << 5) + t] = acc[b];
    }
    __syncthreads();
    for (int c = tid; c < 1024; c += WG) {
        float s = stage[c] + stage[1024 + c] + stage[2048 + c] + stage[3072 + c];
        unsafeAtomicAdd(&out[(g << 10) + c], s);
    }
}

extern "C" void kernel_launch(void* const* d_in, const int* in_sizes, int n_in,
                              void* d_out, int out_size, void* d_ws, size_t ws_size,
                              hipStream_t stream) {
    const float* x     = (const float*)d_in[0];
    const float* v     = (const float*)d_in[1];
    const float* lin   = (const float*)d_in[2];
    const int*   edge  = (const int*)d_in[3];
    const int*   batch = (const int*)d_in[4];
    int N = in_sizes[4];
    int E = in_sizes[3] / 2;

    float* out = (float*)d_out;

    // workspace layout (all 4B-aligned)
    float* ehs     = (float*)d_ws;              // E*32 floats
    int*   eg      = (int*)(ehs + (size_t)E * 32);  // E
    int*   perm    = eg + E;                    // E
    int*   cnt     = perm + E;                  // 64
    int*   offs    = cnt + G64;                 // 65
    int*   cursor  = offs + G64 + 1;            // 64
    int*   node_off= cursor + G64;              // 65

    hipMemsetAsync(out, 0, (size_t)out_size * sizeof(float), stream);
    hipMemsetAsync(cnt, 0, G64 * sizeof(int), stream);

    k_hist<<<(E + WG - 1) / WG, WG, 0, stream>>>(edge, batch, eg, cnt, E);
    k_scan<<<1, 128, 0, stream>>>(batch, cnt, offs, cursor, node_off, N);
    k_scatter<<<(E + WG - 1) / WG, WG, 0, stream>>>(eg, cursor, perm, E);
    k_eh2<<<((size_t)E * 32 + WG - 1) / WG, WG, 0, stream>>>(perm, edge, x, v, ehs, E);

    dim3 grid(G64, SPLITS);
    k_acc<<<grid, WG, 0, stream>>>(x, v, ehs, lin, offs, node_off, out);
}